// Round 13
// baseline (182.009 us; speedup 1.0000x reference)
//
#include <hip/hip_runtime.h>
#include <math.h>

typedef unsigned short u16;
typedef unsigned int u32;
typedef unsigned long long u64;
typedef float f32x4 __attribute__((ext_vector_type(4)));
typedef __bf16 bf16x8 __attribute__((ext_vector_type(8)));
typedef __bf16 bf16x4 __attribute__((ext_vector_type(4)));

constexpr int Bc = 4, Lc = 2048, Dc = 512, Hc = 8, DHc = 64;
constexpr int NTOK = Bc * Lc;          // 8192
constexpr float LN_EPS = 1e-5f;
constexpr int KS = 72;                 // gemm LDS row stride
constexpr int PS2 = 136;               // attn P row stride (128 keys + pad, 16B-aligned)
// fold 1/sqrt(Dh) * log2(e) into Q so softmax runs in exp2 domain
constexpr float QSCALE = 0.125f * 1.44269504088896340736f;
constexpr float MNEG = -1e30f;         // finite "-inf" for running max

__device__ inline u16 bf_bits(float f) {
  return __builtin_bit_cast(u16, (__bf16)f);
}

// ---------------------------------------------------------------------------
// prep: blocks 0..1023 convert the 4 weight matrices fp32->bf16;
//       blocks 1024..1055 build pad bitmasks pm[b*32+kt] over 64 keys.
// ---------------------------------------------------------------------------
__global__ __launch_bounds__(256) void prep_kernel(const float* __restrict__ s0,
                                                   const float* __restrict__ s1,
                                                   const float* __restrict__ s2,
                                                   const float* __restrict__ s3,
                                                   u16* __restrict__ d0,
                                                   u16* __restrict__ d1,
                                                   u16* __restrict__ d2,
                                                   u16* __restrict__ d3,
                                                   const int* __restrict__ tok,
                                                   u64* __restrict__ pm) {
  int bid = blockIdx.x;
  if (bid < 1024) {
    int mat = bid >> 8;
    int i = ((bid & 255) * 256 + threadIdx.x) * 4;
    const float* s = (mat == 0) ? s0 : (mat == 1) ? s1 : (mat == 2) ? s2 : s3;
    u16* d = (mat == 0) ? d0 : (mat == 1) ? d1 : (mat == 2) ? d2 : d3;
    float4 v = *(const float4*)&s[i];
    bf16x4 o;
    o[0] = (__bf16)v.x; o[1] = (__bf16)v.y; o[2] = (__bf16)v.z; o[3] = (__bf16)v.w;
    *(bf16x4*)&d[i] = o;
  } else {
    int wid = ((bid - 1024) * 256 + threadIdx.x) >> 6;   // 0..127
    int lane = threadIdx.x & 63;
    u64 m = __ballot(tok[(size_t)wid * 64 + lane] == 0);
    if (lane == 0) pm[wid] = m;
  }
}

// ---------------------------------------------------------------------------
// LayerNorm: one wave per row of 512, bf16 output
// ---------------------------------------------------------------------------
__global__ __launch_bounds__(256) void ln_kernel(const float* __restrict__ x,
                                                 const float* __restrict__ gamma,
                                                 const float* __restrict__ beta,
                                                 u16* __restrict__ xn) {
  int wave = threadIdx.x >> 6;
  int lane = threadIdx.x & 63;
  int row  = blockIdx.x * 4 + wave;
  const float* xr = x + (size_t)row * Dc;
  float4 v0 = ((const float4*)xr)[lane * 2];
  float4 v1 = ((const float4*)xr)[lane * 2 + 1];
  float sum = v0.x + v0.y + v0.z + v0.w + v1.x + v1.y + v1.z + v1.w;
  float sq  = v0.x*v0.x + v0.y*v0.y + v0.z*v0.z + v0.w*v0.w
            + v1.x*v1.x + v1.y*v1.y + v1.z*v1.z + v1.w*v1.w;
  #pragma unroll
  for (int off = 32; off > 0; off >>= 1) {
    sum += __shfl_xor(sum, off);
    sq  += __shfl_xor(sq, off);
  }
  float mu = sum * (1.0f / Dc);
  float rs = rsqrtf(sq * (1.0f / Dc) - mu * mu + LN_EPS);
  float4 g0 = ((const float4*)gamma)[lane * 2];
  float4 g1 = ((const float4*)gamma)[lane * 2 + 1];
  float4 b0 = ((const float4*)beta)[lane * 2];
  float4 b1 = ((const float4*)beta)[lane * 2 + 1];
  bf16x8 o;
  o[0] = (__bf16)((v0.x - mu) * rs * g0.x + b0.x);
  o[1] = (__bf16)((v0.y - mu) * rs * g0.y + b0.y);
  o[2] = (__bf16)((v0.z - mu) * rs * g0.z + b0.z);
  o[3] = (__bf16)((v0.w - mu) * rs * g0.w + b0.w);
  o[4] = (__bf16)((v1.x - mu) * rs * g1.x + b1.x);
  o[5] = (__bf16)((v1.y - mu) * rs * g1.y + b1.y);
  o[6] = (__bf16)((v1.z - mu) * rs * g1.z + b1.z);
  o[7] = (__bf16)((v1.w - mu) * rs * g1.w + b1.w);
  *(bf16x8*)&xn[(size_t)row * Dc + lane * 8] = o;
}

// ---------------------------------------------------------------------------
// bf16 MFMA GEMM: C[n][e] = sum_d A[n][d] * W[e][d]
// MODE 0: fp32 out [NTOK][Dc] + residual.
// MODE 3: fused QKV. mat0 -> Q (QSCALE, [B][H][L][DH]); mat1 -> K (same);
//         mat2 -> V blocked [B][H][L/64][DH][64] + atomic column-sum -> vm.
// ---------------------------------------------------------------------------
template <int MODE>
__global__ __launch_bounds__(256) void gemm_bf16(const u16* __restrict__ A,
                                                 const u16* __restrict__ W,
                                                 const float* __restrict__ res,
                                                 float* __restrict__ out_f,
                                                 u16* __restrict__ o_q,
                                                 u16* __restrict__ o_k,
                                                 u16* __restrict__ o_v,
                                                 float* __restrict__ vm) {
  __shared__ u16 As[128 * KS];
  __shared__ u16 Bs[128 * KS];
  int tid = threadIdx.x;
  int lane = tid & 63;
  int w = tid >> 6;
  int wr = w >> 1, wc = w & 1;
  int cc = lane & 15, rb = lane >> 4;
  int n0 = blockIdx.x * 128;
  int e0 = blockIdx.y * 128;
  f32x4 acc[4][4] = {};
  for (int k0 = 0; k0 < Dc; k0 += 64) {
    #pragma unroll
    for (int u = 0; u < 4; u++) {
      int idx = u * 256 + tid;
      int row = idx >> 3;
      int col = (idx & 7) << 3;
      *(uint4*)&As[row * KS + col] = *(const uint4*)&A[(size_t)(n0 + row) * Dc + k0 + col];
      *(uint4*)&Bs[row * KS + col] = *(const uint4*)&W[(size_t)(e0 + row) * Dc + k0 + col];
    }
    __syncthreads();
    #pragma unroll
    for (int kk = 0; kk < 64; kk += 32) {
      bf16x8 aF[4], bF[4];
      #pragma unroll
      for (int m = 0; m < 4; m++)
        aF[m] = *(bf16x8*)&As[(wr * 64 + m * 16 + cc) * KS + kk + rb * 8];
      #pragma unroll
      for (int n = 0; n < 4; n++)
        bF[n] = *(bf16x8*)&Bs[(wc * 64 + n * 16 + cc) * KS + kk + rb * 8];
      #pragma unroll
      for (int m = 0; m < 4; m++)
        #pragma unroll
        for (int n = 0; n < 4; n++)
          acc[m][n] = __builtin_amdgcn_mfma_f32_16x16x32_bf16(aF[m], bF[n], acc[m][n], 0, 0, 0);
    }
    __syncthreads();
  }
  if (MODE == 3) {
    int bb = n0 >> 11;
    int mat = e0 >> 9;
    int e0c = e0 & 511;
    if (mat == 2) {
      // V blocked: [B][H][L/64][DH][64]; l runs along j -> bf16x4 store
      #pragma unroll
      for (int n = 0; n < 4; n++) {
        int c = e0c + wc * 64 + n * 16 + cc;
        int h = c >> 6, dh = c & 63;
        float cp = 0.f;
        #pragma unroll
        for (int m = 0; m < 4; m++) {
          int l = (n0 + wr * 64 + m * 16 + rb * 4) & (Lc - 1);
          bf16x4 o4;
          o4[0] = (__bf16)acc[m][n][0]; o4[1] = (__bf16)acc[m][n][1];
          o4[2] = (__bf16)acc[m][n][2]; o4[3] = (__bf16)acc[m][n][3];
          size_t addr = ((((size_t)(bb * Hc + h)) * (Lc / 64) + (l >> 6)) * DHc + dh) * 64 + (l & 63);
          *(bf16x4*)&o_v[addr] = o4;
          cp += (acc[m][n][0] + acc[m][n][1]) + (acc[m][n][2] + acc[m][n][3]);
        }
        cp += __shfl_xor(cp, 16);
        cp += __shfl_xor(cp, 32);
        if (lane < 16) atomicAdd(&vm[(bb * Hc + h) * DHc + dh], cp);
      }
    } else {
      float sc = (mat == 0) ? QSCALE : 1.0f;
      u16* dst = (mat == 0) ? o_q : o_k;
      #pragma unroll
      for (int m = 0; m < 4; m++) {
        #pragma unroll
        for (int n = 0; n < 4; n++) {
          #pragma unroll
          for (int j = 0; j < 4; j++) {
            int r = n0 + wr * 64 + m * 16 + rb * 4 + j;
            int c = e0c + wc * 64 + n * 16 + cc;
            int ll = r & (Lc - 1);
            dst[(((size_t)(bb * Hc + (c >> 6))) * Lc + ll) * DHc + (c & 63)] = bf_bits(acc[m][n][j] * sc);
          }
        }
      }
    }
  } else {
    #pragma unroll
    for (int m = 0; m < 4; m++) {
      #pragma unroll
      for (int n = 0; n < 4; n++) {
        #pragma unroll
        for (int j = 0; j < 4; j++) {
          int r = n0 + wr * 64 + m * 16 + rb * 4 + j;
          int c = e0 + wc * 64 + n * 16 + cc;
          size_t o = (size_t)r * Dc + c;
          out_f[o] = acc[m][n][j] + res[o];
        }
      }
    }
  }
}

// ---------------------------------------------------------------------------
// Flash attention v10: QBLK=16, KVBLK=128 — same S-elements/lane/tile as the
// 32x64 variants but HALF the fixed per-tile overhead (loop iters, lgkmcnt
// stops, votes, P rounds). One wave per (bh, qt), qt-strided heavy-first, no
// partials/merge (r9/r12 showed chunk+merge is a net loss). QK^T in two 4-c
// halves keeps transient kf <=32 dwords (natural VGPR ~115, NO occupancy
// attributes — r10/r11 proved forcing the budget spills).
// ---------------------------------------------------------------------------
__global__ __launch_bounds__(64) void attn10(const u16* __restrict__ Q,
                                             const u16* __restrict__ K,
                                             const u16* __restrict__ VT,
                                             const float* __restrict__ vm,
                                             const u64* __restrict__ pmask,
                                             u16* __restrict__ out) {
  __shared__ u16 Ps[16 * PS2];
  int lane = threadIdx.x;
  int cc = lane & 15, rb = lane >> 4;
  int bh = blockIdx.x;
  int qt = 127 - (int)blockIdx.y;                   // heavy q-tiles first
  int q0 = qt * 16;
  int b = bh >> 3, h = bh & 7;
  const u16* Qb = Q + (size_t)bh * Lc * DHc;
  const u16* Kb = K + (size_t)bh * Lc * DHc;
  const u16* Vb = VT + (size_t)bh * Lc * DHc;       // blocked [L/64][DH][64]
  const u64* pmb = pmask + (b << 5);
  int nt = (q0 >> 7) + 1;                           // 128-key tiles

  bf16x8 qF[2];
  #pragma unroll
  for (int kc = 0; kc < 2; kc++)
    qF[kc] = *(const bf16x8*)&Qb[(size_t)(q0 + cc) * DHc + kc * 32 + rb * 8];

  float mrow = MNEG;
  float lrow = 0.f;                                 // per-lane PARTIAL sum
  f32x4 acc[4] = {};

  for (int kt = 0; kt < nt; kt++) {
    int k0 = kt << 7;
    bool last = (kt == nt - 1);
    u64 pm0 = pmb[kt * 2];
    u64 pm1 = pmb[kt * 2 + 1];
    f32x4 sq[8] = {};
    // QK^T over 128 keys in two 4-c halves (kf transient: 32 dwords peak)
    #pragma unroll
    for (int hf = 0; hf < 2; hf++) {
      const u16* kp = Kb + (size_t)(k0 + hf * 64) * DHc;
      bf16x8 kf[4][2];
      #pragma unroll
      for (int c = 0; c < 4; c++) {
        kf[c][0] = *(const bf16x8*)&kp[(c * 16 + cc) * DHc + rb * 8];
        kf[c][1] = *(const bf16x8*)&kp[(c * 16 + cc) * DHc + 32 + rb * 8];
      }
      __builtin_amdgcn_s_setprio(1);
      #pragma unroll
      for (int c = 0; c < 4; c++) {
        sq[hf * 4 + c] = __builtin_amdgcn_mfma_f32_16x16x32_bf16(kf[c][0], qF[0], sq[hf * 4 + c], 0, 0, 0);
        sq[hf * 4 + c] = __builtin_amdgcn_mfma_f32_16x16x32_bf16(kf[c][1], qF[1], sq[hf * 4 + c], 0, 0, 0);
      }
      __builtin_amdgcn_s_setprio(0);
    }
    __builtin_amdgcn_sched_barrier(0);   // keep V loads below QK^T (reg reuse)
    // V pass-0 loads: issued now, consumed after softmax
    const u16* vp0 = Vb + (size_t)(kt * 2) * (DHc * 64);
    bf16x8 vf[2][4];
    #pragma unroll
    for (int kc = 0; kc < 2; kc++)
      #pragma unroll
      for (int d0 = 0; d0 < 4; d0++)
        vf[kc][d0] = *(const bf16x8*)&vp0[(d0 * 16 + cc) * 64 + kc * 32 + rb * 8];

    if (pm0 | pm1) {                               // pad mask: ~never taken
      #pragma unroll
      for (int c = 0; c < 8; c++) {
        u64 pmw = (c < 4) ? pm0 : pm1;
        u32 smr = (((u32)(pmw >> ((c & 3) * 16)) & 0xffffu) >> (rb * 4));
        #pragma unroll
        for (int j = 0; j < 4; j++)
          if ((smr >> j) & 1) sq[c][j] = -INFINITY;
      }
    }
    if (last) {                                    // causal boundary tile
      int qrel = (q0 & 127) + cc;
      #pragma unroll
      for (int c = 0; c < 8; c++)
        #pragma unroll
        for (int j = 0; j < 4; j++)
          if (c * 16 + rb * 4 + j > qrel) sq[c][j] = -INFINITY;
    }
    // online softmax: shuffle-free common path, one vote per 128 keys
    {
      float mh[8];
      #pragma unroll
      for (int c = 0; c < 8; c++)
        mh[c] = fmaxf(fmaxf(sq[c][0], sq[c][1]), fmaxf(sq[c][2], sq[c][3]));
      float mx = fmaxf(fmaxf(fmaxf(mh[0], mh[1]), fmaxf(mh[2], mh[3])),
                       fmaxf(fmaxf(mh[4], mh[5]), fmaxf(mh[6], mh[7])));
      if (!__all(mx <= mrow + 8.f)) {
        float mf = fmaxf(mx, __shfl_xor(mx, 16));
        mf = fmaxf(mf, __shfl_xor(mf, 32));
        float nm = fmaxf(mrow, mf);
        float alpha = exp2f(mrow - nm);
        lrow *= alpha;
        #pragma unroll
        for (int d0 = 0; d0 < 4; d0++)
          #pragma unroll
          for (int j = 0; j < 4; j++)
            acc[d0][j] *= alpha;
        mrow = nm;
      }
      float rs = 0.f;
      #pragma unroll
      for (int c = 0; c < 8; c++) {
        f32x4 p;
        #pragma unroll
        for (int j = 0; j < 4; j++) p[j] = exp2f(sq[c][j] - mrow);
        rs += (p[0] + p[1]) + (p[2] + p[3]);
        bf16x4 p4;
        p4[0] = (__bf16)p[0]; p4[1] = (__bf16)p[1];
        p4[2] = (__bf16)p[2]; p4[3] = (__bf16)p[3];
        *(bf16x4*)&Ps[cc * PS2 + c * 16 + rb * 4] = p4;
      }
      lrow += rs;                                  // partial: reduced at end
    }
    asm volatile("s_waitcnt lgkmcnt(0)" ::: "memory");   // wave-local RAW on Ps
    __builtin_amdgcn_sched_barrier(0);                   // rule #18
    // PV pass 0 (keys k0..k0+63)
    __builtin_amdgcn_s_setprio(1);
    #pragma unroll
    for (int kc = 0; kc < 2; kc++) {
      bf16x8 pF = *(bf16x8*)&Ps[(size_t)cc * PS2 + kc * 32 + rb * 8];
      #pragma unroll
      for (int d0 = 0; d0 < 4; d0++)
        acc[d0] = __builtin_amdgcn_mfma_f32_16x16x32_bf16(vf[kc][d0], pF, acc[d0], 0, 0, 0);
    }
    __builtin_amdgcn_s_setprio(0);
    // V pass-1 loads + PV pass 1 (keys k0+64..k0+127)
    const u16* vp1 = Vb + (size_t)(kt * 2 + 1) * (DHc * 64);
    #pragma unroll
    for (int kc = 0; kc < 2; kc++)
      #pragma unroll
      for (int d0 = 0; d0 < 4; d0++)
        vf[kc][d0] = *(const bf16x8*)&vp1[(d0 * 16 + cc) * 64 + kc * 32 + rb * 8];
    __builtin_amdgcn_s_setprio(1);
    #pragma unroll
    for (int kc = 0; kc < 2; kc++) {
      bf16x8 pF = *(bf16x8*)&Ps[(size_t)cc * PS2 + 64 + kc * 32 + rb * 8];
      #pragma unroll
      for (int d0 = 0; d0 < 4; d0++)
        acc[d0] = __builtin_amdgcn_mfma_f32_16x16x32_bf16(vf[kc][d0], pF, acc[d0], 0, 0, 0);
    }
    __builtin_amdgcn_s_setprio(0);
  }

  // reduce partial l across rb groups (once per wave)
  lrow += __shfl_xor(lrow, 16);
  lrow += __shfl_xor(lrow, 32);

  // epilogue: normalize; all-masked rows -> uniform mean of ALL V rows
  {
    int q = q0 + cc;
    bool ok = lrow > 0.f;
    float inv = ok ? 1.0f / lrow : 0.f;
    #pragma unroll
    for (int d0 = 0; d0 < 4; d0++) {
      bf16x4 o4;
      #pragma unroll
      for (int j = 0; j < 4; j++) {
        float v = ok ? acc[d0][j] * inv
                     : vm[bh * DHc + d0 * 16 + rb * 4 + j] * (1.0f / Lc);
        o4[j] = (__bf16)v;
      }
      *(bf16x4*)&out[((size_t)(b * Lc + q)) * Dc + h * DHc + d0 * 16 + rb * 4] = o4;
    }
  }
}

// ---------------------------------------------------------------------------
// Launch
// ---------------------------------------------------------------------------
extern "C" void kernel_launch(void* const* d_in, const int* in_sizes, int n_in,
                              void* d_out, int out_size, void* d_ws, size_t ws_size,
                              hipStream_t stream) {
  const float* x     = (const float*)d_in[0];
  const int*   tok   = (const int*)d_in[1];
  const float* Wq    = (const float*)d_in[2];
  const float* Wk    = (const float*)d_in[3];
  const float* Wv    = (const float*)d_in[4];
  const float* Wo    = (const float*)d_in[5];
  const float* gamma = (const float*)d_in[6];
  const float* beta  = (const float*)d_in[7];
  float* out = (float*)d_out;

  const size_t SEG = (size_t)NTOK * Dc;     // 4,194,304 elems
  const size_t WSEG = (size_t)Dc * Dc;      // 262,144 elems
  u16* xn   = (u16*)d_ws;
  u16* Qd   = xn + SEG;
  u16* Kd   = Qd + SEG;
  u16* VT   = Kd + SEG;                     // blocked [B][H][L/64][DH][64]
  u16* ao   = VT + SEG;
  u16* Wqkv = ao + SEG;                     // 3*WSEG (Q,K,V rows stacked)
  u16* Wob  = Wqkv + 3 * WSEG;
  float* vm = (float*)(Wob + WSEG);         // 2048 f32
  u64* pmarr = (u64*)(vm + (size_t)Bc * Hc * DHc);  // 128 u64

  (void)hipMemsetAsync(vm, 0, (size_t)Bc * Hc * DHc * sizeof(float), stream);

  prep_kernel<<<1056, 256, 0, stream>>>(Wq, Wk, Wv, Wo,
                                        Wqkv, Wqkv + WSEG, Wqkv + 2 * WSEG, Wob,
                                        tok, pmarr);
  ln_kernel<<<NTOK / 4, 256, 0, stream>>>(x, gamma, beta, xn);

  dim3 gq(NTOK / 128, (3 * Dc) / 128);      // 64 x 12
  gemm_bf16<3><<<gq, 256, 0, stream>>>(xn, Wqkv, nullptr, nullptr, Qd, Kd, VT, vm);

  dim3 ga(Bc * Hc, 128);                    // 32 x 128 one-wave blocks
  attn10<<<ga, 64, 0, stream>>>(Qd, Kd, VT, vm, pmarr, ao);

  dim3 gg(NTOK / 128, Dc / 128);            // 64 x 4
  gemm_bf16<0><<<gg, 256, 0, stream>>>(ao, Wob, x, out, nullptr, nullptr, nullptr, nullptr);
}

// Round 14
// 120.200 us; speedup vs baseline: 1.5142x; 1.5142x over previous
//
#include <hip/hip_runtime.h>
#include <math.h>

typedef unsigned short u16;
typedef unsigned int u32;
typedef unsigned long long u64;
typedef float f32x4 __attribute__((ext_vector_type(4)));
typedef __bf16 bf16x8 __attribute__((ext_vector_type(8)));
typedef __bf16 bf16x4 __attribute__((ext_vector_type(4)));

constexpr int Bc = 4, Lc = 2048, Dc = 512, Hc = 8, DHc = 64;
constexpr int NTOK = Bc * Lc;          // 8192
constexpr float LN_EPS = 1e-5f;
constexpr int KS = 72;                 // gemm LDS row stride
constexpr int PS = 72;                 // attn P-scratch row stride
// fold 1/sqrt(Dh) * log2(e) into Q so softmax runs in exp2 domain
constexpr float QSCALE = 0.125f * 1.44269504088896340736f;
constexpr float MNEG = -1e30f;         // finite "-inf" for running max

__device__ inline u16 bf_bits(float f) {
  return __builtin_bit_cast(u16, (__bf16)f);
}

// ---------------------------------------------------------------------------
// prep: blocks 0..1023 convert the 4 weight matrices fp32->bf16;
//       blocks 1024..1055 build pad bitmasks pm[b*32+kt] over 64 keys.
// ---------------------------------------------------------------------------
__global__ __launch_bounds__(256) void prep_kernel(const float* __restrict__ s0,
                                                   const float* __restrict__ s1,
                                                   const float* __restrict__ s2,
                                                   const float* __restrict__ s3,
                                                   u16* __restrict__ d0,
                                                   u16* __restrict__ d1,
                                                   u16* __restrict__ d2,
                                                   u16* __restrict__ d3,
                                                   const int* __restrict__ tok,
                                                   u64* __restrict__ pm) {
  int bid = blockIdx.x;
  if (bid < 1024) {
    int mat = bid >> 8;
    int i = ((bid & 255) * 256 + threadIdx.x) * 4;
    const float* s = (mat == 0) ? s0 : (mat == 1) ? s1 : (mat == 2) ? s2 : s3;
    u16* d = (mat == 0) ? d0 : (mat == 1) ? d1 : (mat == 2) ? d2 : d3;
    float4 v = *(const float4*)&s[i];
    bf16x4 o;
    o[0] = (__bf16)v.x; o[1] = (__bf16)v.y; o[2] = (__bf16)v.z; o[3] = (__bf16)v.w;
    *(bf16x4*)&d[i] = o;
  } else {
    int wid = ((bid - 1024) * 256 + threadIdx.x) >> 6;   // 0..127
    int lane = threadIdx.x & 63;
    u64 m = __ballot(tok[(size_t)wid * 64 + lane] == 0);
    if (lane == 0) pm[wid] = m;
  }
}

// ---------------------------------------------------------------------------
// LayerNorm: one wave per row of 512, bf16 output
// ---------------------------------------------------------------------------
__global__ __launch_bounds__(256) void ln_kernel(const float* __restrict__ x,
                                                 const float* __restrict__ gamma,
                                                 const float* __restrict__ beta,
                                                 u16* __restrict__ xn) {
  int wave = threadIdx.x >> 6;
  int lane = threadIdx.x & 63;
  int row  = blockIdx.x * 4 + wave;
  const float* xr = x + (size_t)row * Dc;
  float4 v0 = ((const float4*)xr)[lane * 2];
  float4 v1 = ((const float4*)xr)[lane * 2 + 1];
  float sum = v0.x + v0.y + v0.z + v0.w + v1.x + v1.y + v1.z + v1.w;
  float sq  = v0.x*v0.x + v0.y*v0.y + v0.z*v0.z + v0.w*v0.w
            + v1.x*v1.x + v1.y*v1.y + v1.z*v1.z + v1.w*v1.w;
  #pragma unroll
  for (int off = 32; off > 0; off >>= 1) {
    sum += __shfl_xor(sum, off);
    sq  += __shfl_xor(sq, off);
  }
  float mu = sum * (1.0f / Dc);
  float rs = rsqrtf(sq * (1.0f / Dc) - mu * mu + LN_EPS);
  float4 g0 = ((const float4*)gamma)[lane * 2];
  float4 g1 = ((const float4*)gamma)[lane * 2 + 1];
  float4 b0 = ((const float4*)beta)[lane * 2];
  float4 b1 = ((const float4*)beta)[lane * 2 + 1];
  bf16x8 o;
  o[0] = (__bf16)((v0.x - mu) * rs * g0.x + b0.x);
  o[1] = (__bf16)((v0.y - mu) * rs * g0.y + b0.y);
  o[2] = (__bf16)((v0.z - mu) * rs * g0.z + b0.z);
  o[3] = (__bf16)((v0.w - mu) * rs * g0.w + b0.w);
  o[4] = (__bf16)((v1.x - mu) * rs * g1.x + b1.x);
  o[5] = (__bf16)((v1.y - mu) * rs * g1.y + b1.y);
  o[6] = (__bf16)((v1.z - mu) * rs * g1.z + b1.z);
  o[7] = (__bf16)((v1.w - mu) * rs * g1.w + b1.w);
  *(bf16x8*)&xn[(size_t)row * Dc + lane * 8] = o;
}

// ---------------------------------------------------------------------------
// bf16 MFMA GEMM: C[n][e] = sum_d A[n][d] * W[e][d]
// MODE 0: fp32 out [NTOK][Dc] + residual.
// MODE 3: fused QKV. mat0 -> Q (QSCALE, [B][H][L][DH]); mat1 -> K (same);
//         mat2 -> V blocked [B][H][L/64][DH][64] + atomic column-sum -> vm.
// ---------------------------------------------------------------------------
template <int MODE>
__global__ __launch_bounds__(256) void gemm_bf16(const u16* __restrict__ A,
                                                 const u16* __restrict__ W,
                                                 const float* __restrict__ res,
                                                 float* __restrict__ out_f,
                                                 u16* __restrict__ o_q,
                                                 u16* __restrict__ o_k,
                                                 u16* __restrict__ o_v,
                                                 float* __restrict__ vm) {
  __shared__ u16 As[128 * KS];
  __shared__ u16 Bs[128 * KS];
  int tid = threadIdx.x;
  int lane = tid & 63;
  int w = tid >> 6;
  int wr = w >> 1, wc = w & 1;
  int cc = lane & 15, rb = lane >> 4;
  int n0 = blockIdx.x * 128;
  int e0 = blockIdx.y * 128;
  f32x4 acc[4][4] = {};
  for (int k0 = 0; k0 < Dc; k0 += 64) {
    #pragma unroll
    for (int u = 0; u < 4; u++) {
      int idx = u * 256 + tid;
      int row = idx >> 3;
      int col = (idx & 7) << 3;
      *(uint4*)&As[row * KS + col] = *(const uint4*)&A[(size_t)(n0 + row) * Dc + k0 + col];
      *(uint4*)&Bs[row * KS + col] = *(const uint4*)&W[(size_t)(e0 + row) * Dc + k0 + col];
    }
    __syncthreads();
    #pragma unroll
    for (int kk = 0; kk < 64; kk += 32) {
      bf16x8 aF[4], bF[4];
      #pragma unroll
      for (int m = 0; m < 4; m++)
        aF[m] = *(bf16x8*)&As[(wr * 64 + m * 16 + cc) * KS + kk + rb * 8];
      #pragma unroll
      for (int n = 0; n < 4; n++)
        bF[n] = *(bf16x8*)&Bs[(wc * 64 + n * 16 + cc) * KS + kk + rb * 8];
      #pragma unroll
      for (int m = 0; m < 4; m++)
        #pragma unroll
        for (int n = 0; n < 4; n++)
          acc[m][n] = __builtin_amdgcn_mfma_f32_16x16x32_bf16(aF[m], bF[n], acc[m][n], 0, 0, 0);
    }
    __syncthreads();
  }
  if (MODE == 3) {
    int bb = n0 >> 11;
    int mat = e0 >> 9;
    int e0c = e0 & 511;
    if (mat == 2) {
      // V blocked: [B][H][L/64][DH][64]; l runs along j -> bf16x4 store
      #pragma unroll
      for (int n = 0; n < 4; n++) {
        int c = e0c + wc * 64 + n * 16 + cc;
        int h = c >> 6, dh = c & 63;
        float cp = 0.f;
        #pragma unroll
        for (int m = 0; m < 4; m++) {
          int l = (n0 + wr * 64 + m * 16 + rb * 4) & (Lc - 1);
          bf16x4 o4;
          o4[0] = (__bf16)acc[m][n][0]; o4[1] = (__bf16)acc[m][n][1];
          o4[2] = (__bf16)acc[m][n][2]; o4[3] = (__bf16)acc[m][n][3];
          size_t addr = ((((size_t)(bb * Hc + h)) * (Lc / 64) + (l >> 6)) * DHc + dh) * 64 + (l & 63);
          *(bf16x4*)&o_v[addr] = o4;
          cp += (acc[m][n][0] + acc[m][n][1]) + (acc[m][n][2] + acc[m][n][3]);
        }
        cp += __shfl_xor(cp, 16);
        cp += __shfl_xor(cp, 32);
        if (lane < 16) atomicAdd(&vm[(bb * Hc + h) * DHc + dh], cp);
      }
    } else {
      float sc = (mat == 0) ? QSCALE : 1.0f;
      u16* dst = (mat == 0) ? o_q : o_k;
      #pragma unroll
      for (int m = 0; m < 4; m++) {
        #pragma unroll
        for (int n = 0; n < 4; n++) {
          #pragma unroll
          for (int j = 0; j < 4; j++) {
            int r = n0 + wr * 64 + m * 16 + rb * 4 + j;
            int c = e0c + wc * 64 + n * 16 + cc;
            int ll = r & (Lc - 1);
            dst[(((size_t)(bb * Hc + (c >> 6))) * Lc + ll) * DHc + (c & 63)] = bf_bits(acc[m][n][j] * sc);
          }
        }
      }
    }
  } else {
    #pragma unroll
    for (int m = 0; m < 4; m++) {
      #pragma unroll
      for (int n = 0; n < 4; n++) {
        #pragma unroll
        for (int j = 0; j < 4; j++) {
          int r = n0 + wr * 64 + m * 16 + rb * 4 + j;
          int c = e0 + wc * 64 + n * 16 + cc;
          size_t o = (size_t)r * Dc + c;
          out_f[o] = acc[m][n][j] + res[o];
        }
      }
    }
  }
}

// ---------------------------------------------------------------------------
// Flash attention v11 = r6's proven attn3 (72.4us) + 2-deep K prefetch
// (two NAMED kf buffers, loop unrolled x2 — no runtime-indexed arrays) +
// blocked V tiles. One wave per (bh, qt), QBLK=32, KVBLK=64, heavy-first.
// No occupancy attributes (r10/r11: forcing the budget spills).
// ---------------------------------------------------------------------------
__global__ __launch_bounds__(64) void attn11(const u16* __restrict__ Q,
                                             const u16* __restrict__ K,
                                             const u16* __restrict__ VT,
                                             const float* __restrict__ vm,
                                             const u64* __restrict__ pmask,
                                             u16* __restrict__ out) {
  __shared__ u16 Ps[32 * PS];
  int lane = threadIdx.x;
  int cc = lane & 15, rb = lane >> 4;
  int bh = blockIdx.x;
  int qt = (int)gridDim.y - 1 - (int)blockIdx.y;     // heavy q-tiles first
  int q0 = qt * 32;
  int b = bh >> 3, h = bh & 7;
  const u16* Qb = Q + (size_t)bh * Lc * DHc;
  const u16* Kb = K + (size_t)bh * Lc * DHc;
  const u16* Vb = VT + (size_t)bh * Lc * DHc;        // blocked [L/64][DH][64]
  const u64* pmb = pmask + (b << 5);
  int nfull = q0 >> 6;                               // last tile index

  bf16x8 qF[2][2];
  #pragma unroll
  for (int qb = 0; qb < 2; qb++)
    #pragma unroll
    for (int kc = 0; kc < 2; kc++)
      qF[qb][kc] = *(const bf16x8*)&Qb[(size_t)(q0 + qb * 16 + cc) * DHc + kc * 32 + rb * 8];

  float mrow[2] = {MNEG, MNEG};
  float lrow[2] = {0.f, 0.f};
  f32x4 acc[2][4] = {};

  bf16x8 kfA[4][2], kfB[4][2];
  // preload K tiles 0 and 1
  {
    const u16* kp = Kb;
    #pragma unroll
    for (int c = 0; c < 4; c++) {
      kfA[c][0] = *(const bf16x8*)&kp[(c * 16 + cc) * DHc + rb * 8];
      kfA[c][1] = *(const bf16x8*)&kp[(c * 16 + cc) * DHc + 32 + rb * 8];
    }
  }
  if (nfull >= 1) {
    const u16* kp = Kb + (size_t)64 * DHc;
    #pragma unroll
    for (int c = 0; c < 4; c++) {
      kfB[c][0] = *(const bf16x8*)&kp[(c * 16 + cc) * DHc + rb * 8];
      kfB[c][1] = *(const bf16x8*)&kp[(c * 16 + cc) * DHc + 32 + rb * 8];
    }
  }

  auto body = [&](int kt, bf16x8 (&kf)[4][2]) {
    int k0 = kt * 64;
    bool last = (kt == nfull);
    u64 pm = pmb[kt];
    // V tile: contiguous 8KB block, issue early (consumed at PV)
    const u16* vp = Vb + (size_t)kt * (DHc * 64);
    bf16x8 vf[2][4];
    #pragma unroll
    for (int kc = 0; kc < 2; kc++)
      #pragma unroll
      for (int d0 = 0; d0 < 4; d0++)
        vf[kc][d0] = *(const bf16x8*)&vp[(d0 * 16 + cc) * 64 + kc * 32 + rb * 8];

    // S^T = K·Q^T (log2 domain; Q carries 0.125*log2e)
    f32x4 sq[2][4] = {};
    __builtin_amdgcn_s_setprio(1);
    #pragma unroll
    for (int c = 0; c < 4; c++) {
      #pragma unroll
      for (int qb = 0; qb < 2; qb++) {
        sq[qb][c] = __builtin_amdgcn_mfma_f32_16x16x32_bf16(kf[c][0], qF[qb][0], sq[qb][c], 0, 0, 0);
        sq[qb][c] = __builtin_amdgcn_mfma_f32_16x16x32_bf16(kf[c][1], qF[qb][1], sq[qb][c], 0, 0, 0);
      }
    }
    __builtin_amdgcn_s_setprio(0);
    // kf now dead — prefetch K tile kt+2 into the SAME buffer
    if (kt + 2 <= nfull) {
      const u16* kp = Kb + (size_t)(k0 + 128) * DHc;
      #pragma unroll
      for (int c = 0; c < 4; c++) {
        kf[c][0] = *(const bf16x8*)&kp[(c * 16 + cc) * DHc + rb * 8];
        kf[c][1] = *(const bf16x8*)&kp[(c * 16 + cc) * DHc + 32 + rb * 8];
      }
    }
    if (pm) {                                      // pad mask: ~never taken
      #pragma unroll
      for (int c = 0; c < 4; c++) {
        u32 smr = (((u32)(pm >> (c * 16)) & 0xffffu) >> (rb * 4));
        #pragma unroll
        for (int qb = 0; qb < 2; qb++)
          #pragma unroll
          for (int j = 0; j < 4; j++)
            if ((smr >> j) & 1) sq[qb][c][j] = -INFINITY;
      }
    }
    if (last) {                                    // causal boundary tile
      #pragma unroll
      for (int qb = 0; qb < 2; qb++) {
        int qrel = q0 + qb * 16 + cc - k0;
        #pragma unroll
        for (int c = 0; c < 4; c++)
          #pragma unroll
          for (int j = 0; j < 4; j++)
            if (c * 16 + rb * 4 + j > qrel) sq[qb][c][j] = -INFINITY;
      }
    }
    // online softmax (defer-max THR=8, exp2 domain) — r6-proven form
    #pragma unroll
    for (int qb = 0; qb < 2; qb++) {
      float m0 = fmaxf(fmaxf(sq[qb][0][0], sq[qb][0][1]), fmaxf(sq[qb][0][2], sq[qb][0][3]));
      float m1 = fmaxf(fmaxf(sq[qb][1][0], sq[qb][1][1]), fmaxf(sq[qb][1][2], sq[qb][1][3]));
      float m2 = fmaxf(fmaxf(sq[qb][2][0], sq[qb][2][1]), fmaxf(sq[qb][2][2], sq[qb][2][3]));
      float m3 = fmaxf(fmaxf(sq[qb][3][0], sq[qb][3][1]), fmaxf(sq[qb][3][2], sq[qb][3][3]));
      float mx = fmaxf(fmaxf(m0, m1), fmaxf(m2, m3));
      mx = fmaxf(mx, __shfl_xor(mx, 16));
      mx = fmaxf(mx, __shfl_xor(mx, 32));
      if (!__all(mx <= mrow[qb] + 8.f)) {
        float nm = fmaxf(mrow[qb], mx);
        float alpha = exp2f(mrow[qb] - nm);
        lrow[qb] *= alpha;
        #pragma unroll
        for (int d0 = 0; d0 < 4; d0++)
          #pragma unroll
          for (int j = 0; j < 4; j++)
            acc[qb][d0][j] *= alpha;
        mrow[qb] = nm;
      }
      float rs = 0.f;
      #pragma unroll
      for (int c = 0; c < 4; c++) {
        f32x4 p;
        #pragma unroll
        for (int j = 0; j < 4; j++) p[j] = exp2f(sq[qb][c][j] - mrow[qb]);
        rs += (p[0] + p[1]) + (p[2] + p[3]);
        bf16x4 p4;
        p4[0] = (__bf16)p[0]; p4[1] = (__bf16)p[1];
        p4[2] = (__bf16)p[2]; p4[3] = (__bf16)p[3];
        *(bf16x4*)&Ps[(qb * 16 + cc) * PS + c * 16 + rb * 4] = p4;
      }
      rs += __shfl_xor(rs, 16);
      rs += __shfl_xor(rs, 32);
      lrow[qb] += rs;
    }
    asm volatile("s_waitcnt lgkmcnt(0)" ::: "memory");   // wave-local RAW on Ps
    __builtin_amdgcn_sched_barrier(0);                   // rule #18
    // O^T += V^T · P^T
    __builtin_amdgcn_s_setprio(1);
    #pragma unroll
    for (int kc = 0; kc < 2; kc++) {
      bf16x8 pF0 = *(bf16x8*)&Ps[(size_t)cc * PS + kc * 32 + rb * 8];
      bf16x8 pF1 = *(bf16x8*)&Ps[(size_t)(16 + cc) * PS + kc * 32 + rb * 8];
      #pragma unroll
      for (int d0 = 0; d0 < 4; d0++) {
        acc[0][d0] = __builtin_amdgcn_mfma_f32_16x16x32_bf16(vf[kc][d0], pF0, acc[0][d0], 0, 0, 0);
        acc[1][d0] = __builtin_amdgcn_mfma_f32_16x16x32_bf16(vf[kc][d0], pF1, acc[1][d0], 0, 0, 0);
      }
    }
    __builtin_amdgcn_s_setprio(0);
  };

  for (int kt = 0; kt <= nfull; kt += 2) {
    body(kt, kfA);
    if (kt + 1 <= nfull) body(kt + 1, kfB);
  }

  // epilogue: normalize; all-masked rows -> uniform mean of ALL V rows
  #pragma unroll
  for (int qb = 0; qb < 2; qb++) {
    int q = q0 + qb * 16 + cc;
    bool ok = lrow[qb] > 0.f;
    float inv = ok ? 1.0f / lrow[qb] : 0.f;
    #pragma unroll
    for (int d0 = 0; d0 < 4; d0++) {
      bf16x4 o4;
      #pragma unroll
      for (int j = 0; j < 4; j++) {
        float v = ok ? acc[qb][d0][j] * inv
                     : vm[bh * DHc + d0 * 16 + rb * 4 + j] * (1.0f / Lc);
        o4[j] = (__bf16)v;
      }
      *(bf16x4*)&out[((size_t)(b * Lc + q)) * Dc + h * DHc + d0 * 16 + rb * 4] = o4;
    }
  }
}

// ---------------------------------------------------------------------------
// Launch
// ---------------------------------------------------------------------------
extern "C" void kernel_launch(void* const* d_in, const int* in_sizes, int n_in,
                              void* d_out, int out_size, void* d_ws, size_t ws_size,
                              hipStream_t stream) {
  const float* x     = (const float*)d_in[0];
  const int*   tok   = (const int*)d_in[1];
  const float* Wq    = (const float*)d_in[2];
  const float* Wk    = (const float*)d_in[3];
  const float* Wv    = (const float*)d_in[4];
  const float* Wo    = (const float*)d_in[5];
  const float* gamma = (const float*)d_in[6];
  const float* beta  = (const float*)d_in[7];
  float* out = (float*)d_out;

  const size_t SEG = (size_t)NTOK * Dc;     // 4,194,304 elems
  const size_t WSEG = (size_t)Dc * Dc;      // 262,144 elems
  u16* xn   = (u16*)d_ws;
  u16* Qd   = xn + SEG;
  u16* Kd   = Qd + SEG;
  u16* VT   = Kd + SEG;                     // blocked [B][H][L/64][DH][64]
  u16* ao   = VT + SEG;
  u16* Wqkv = ao + SEG;                     // 3*WSEG (Q,K,V rows stacked)
  u16* Wob  = Wqkv + 3 * WSEG;
  float* vm = (float*)(Wob + WSEG);         // 2048 f32
  u64* pmarr = (u64*)(vm + (size_t)Bc * Hc * DHc);  // 128 u64

  (void)hipMemsetAsync(vm, 0, (size_t)Bc * Hc * DHc * sizeof(float), stream);

  prep_kernel<<<1056, 256, 0, stream>>>(Wq, Wk, Wv, Wo,
                                        Wqkv, Wqkv + WSEG, Wqkv + 2 * WSEG, Wob,
                                        tok, pmarr);
  ln_kernel<<<NTOK / 4, 256, 0, stream>>>(x, gamma, beta, xn);

  dim3 gq(NTOK / 128, (3 * Dc) / 128);      // 64 x 12
  gemm_bf16<3><<<gq, 256, 0, stream>>>(xn, Wqkv, nullptr, nullptr, Qd, Kd, VT, vm);

  dim3 ga(Bc * Hc, Lc / 32);                // 32 x 64 one-wave blocks
  attn11<<<ga, 64, 0, stream>>>(Qd, Kd, VT, vm, pmarr, ao);

  dim3 gg(NTOK / 128, Dc / 128);            // 64 x 4
  gemm_bf16<0><<<gg, 256, 0, stream>>>(ao, Wob, x, out, nullptr, nullptr, nullptr, nullptr);
}

// Round 15
// 106.529 us; speedup vs baseline: 1.7085x; 1.1283x over previous
//
#include <hip/hip_runtime.h>
#include <math.h>

typedef unsigned short u16;
typedef unsigned int u32;
typedef unsigned long long u64;
typedef float f32x4 __attribute__((ext_vector_type(4)));
typedef __bf16 bf16x8 __attribute__((ext_vector_type(8)));
typedef __bf16 bf16x4 __attribute__((ext_vector_type(4)));

constexpr int Bc = 4, Lc = 2048, Dc = 512, Hc = 8, DHc = 64;
constexpr int NTOK = Bc * Lc;          // 8192
constexpr float LN_EPS = 1e-5f;
constexpr int PS = 72;                 // attn P-scratch row stride
// fold 1/sqrt(Dh) * log2(e) into Q so softmax runs in exp2 domain
constexpr float QSCALE = 0.125f * 1.44269504088896340736f;
constexpr float MNEG = -1e30f;         // finite "-inf" for running max

__device__ inline u16 bf_bits(float f) {
  return __builtin_bit_cast(u16, (__bf16)f);
}

// ---------------------------------------------------------------------------
// prep2 (single dispatch): blocks 0..1023 cvt weights fp32->bf16;
// 1024..1055 pad bitmasks (+ block 1024 zeroes vm); 1056.. LayerNorm.
// ---------------------------------------------------------------------------
__global__ __launch_bounds__(256) void prep2_kernel(const float* __restrict__ s0,
                                                    const float* __restrict__ s1,
                                                    const float* __restrict__ s2,
                                                    const float* __restrict__ s3,
                                                    u16* __restrict__ d0,
                                                    u16* __restrict__ d1,
                                                    u16* __restrict__ d2,
                                                    u16* __restrict__ d3,
                                                    const int* __restrict__ tok,
                                                    u64* __restrict__ pm,
                                                    float* __restrict__ vm,
                                                    const float* __restrict__ x,
                                                    const float* __restrict__ gamma,
                                                    const float* __restrict__ beta,
                                                    u16* __restrict__ xn) {
  int bid = blockIdx.x;
  if (bid < 1024) {
    int mat = bid >> 8;
    int i = ((bid & 255) * 256 + threadIdx.x) * 4;
    const float* s = (mat == 0) ? s0 : (mat == 1) ? s1 : (mat == 2) ? s2 : s3;
    u16* d = (mat == 0) ? d0 : (mat == 1) ? d1 : (mat == 2) ? d2 : d3;
    float4 v = *(const float4*)&s[i];
    bf16x4 o;
    o[0] = (__bf16)v.x; o[1] = (__bf16)v.y; o[2] = (__bf16)v.z; o[3] = (__bf16)v.w;
    *(bf16x4*)&d[i] = o;
  } else if (bid < 1056) {
    int wid = ((bid - 1024) * 256 + threadIdx.x) >> 6;   // 0..127
    int lane = threadIdx.x & 63;
    u64 m = __ballot(tok[(size_t)wid * 64 + lane] == 0);
    if (lane == 0) pm[wid] = m;
    if (bid == 1024) {                                   // zero vm (2048 f32)
      float4 z = make_float4(0.f, 0.f, 0.f, 0.f);
      *(float4*)&vm[threadIdx.x * 8] = z;
      *(float4*)&vm[threadIdx.x * 8 + 4] = z;
    }
  } else {
    int wave = threadIdx.x >> 6;
    int lane = threadIdx.x & 63;
    int row  = (bid - 1056) * 4 + wave;                  // < 8192
    const float* xr = x + (size_t)row * Dc;
    float4 v0 = ((const float4*)xr)[lane * 2];
    float4 v1 = ((const float4*)xr)[lane * 2 + 1];
    float sum = v0.x + v0.y + v0.z + v0.w + v1.x + v1.y + v1.z + v1.w;
    float sq  = v0.x*v0.x + v0.y*v0.y + v0.z*v0.z + v0.w*v0.w
              + v1.x*v1.x + v1.y*v1.y + v1.z*v1.z + v1.w*v1.w;
    #pragma unroll
    for (int off = 32; off > 0; off >>= 1) {
      sum += __shfl_xor(sum, off);
      sq  += __shfl_xor(sq, off);
    }
    float mu = sum * (1.0f / Dc);
    float rs = rsqrtf(sq * (1.0f / Dc) - mu * mu + LN_EPS);
    float4 g0 = ((const float4*)gamma)[lane * 2];
    float4 g1 = ((const float4*)gamma)[lane * 2 + 1];
    float4 b0 = ((const float4*)beta)[lane * 2];
    float4 b1 = ((const float4*)beta)[lane * 2 + 1];
    bf16x8 o;
    o[0] = (__bf16)((v0.x - mu) * rs * g0.x + b0.x);
    o[1] = (__bf16)((v0.y - mu) * rs * g0.y + b0.y);
    o[2] = (__bf16)((v0.z - mu) * rs * g0.z + b0.z);
    o[3] = (__bf16)((v0.w - mu) * rs * g0.w + b0.w);
    o[4] = (__bf16)((v1.x - mu) * rs * g1.x + b1.x);
    o[5] = (__bf16)((v1.y - mu) * rs * g1.y + b1.y);
    o[6] = (__bf16)((v1.z - mu) * rs * g1.z + b1.z);
    o[7] = (__bf16)((v1.w - mu) * rs * g1.w + b1.w);
    *(bf16x8*)&xn[(size_t)row * Dc + lane * 8] = o;
  }
}

// ---------------------------------------------------------------------------
// bf16 MFMA GEMM with global_load_lds double-buffered staging.
// LDS linear [128][64] per matrix; XOR swizzle rule #21: linear dest +
// inverse-swizzled global SOURCE (chunkcol ^ row&7) + same XOR on frag read.
// Counted vmcnt(8) + raw s_barrier keeps next tile's loads in flight.
// MODE 0: fp32 out [NTOK][Dc] + residual.
// MODE 3: fused QKV. mat0 -> Q (QSCALE, [B][H][L][DH]); mat1 -> K (same);
//         mat2 -> V blocked [B][H][L/64][DH][64] + atomic column-sum -> vm.
// ---------------------------------------------------------------------------
template <int MODE>
__global__ __launch_bounds__(256) void gemm_bf16(const u16* __restrict__ A,
                                                 const u16* __restrict__ W,
                                                 const float* __restrict__ res,
                                                 float* __restrict__ out_f,
                                                 u16* __restrict__ o_q,
                                                 u16* __restrict__ o_k,
                                                 u16* __restrict__ o_v,
                                                 float* __restrict__ vm) {
  __shared__ u16 As[2][128 * 64];
  __shared__ u16 Bs[2][128 * 64];
  int tid = threadIdx.x;
  int lane = tid & 63;
  int w = tid >> 6;
  int wr = w >> 1, wc = w & 1;
  int cc = lane & 15, rb = lane >> 4;
  int n0 = blockIdx.x * 128;
  int e0 = blockIdx.y * 128;

  // stage one 128x64 tile of A and W into buffer buf (8 loads/thread-wave)
  auto stage = [&](int k0, int buf) {
    #pragma unroll
    for (int i = 0; i < 4; i++) {
      int s = (i * 4 + w) * 64 + lane;           // chunk 0..1023
      int row = s >> 3;
      int colp = (s & 7) ^ (row & 7);            // inverse-swizzled source
      const char* gA = (const char*)&A[(size_t)(n0 + row) * Dc + k0] + colp * 16;
      const char* gB = (const char*)&W[(size_t)(e0 + row) * Dc + k0] + colp * 16;
      __builtin_amdgcn_global_load_lds(
          (const __attribute__((address_space(1))) void*)gA,
          (__attribute__((address_space(3))) void*)&As[buf][(i * 4 + w) * 512], 16, 0, 0);
      __builtin_amdgcn_global_load_lds(
          (const __attribute__((address_space(1))) void*)gB,
          (__attribute__((address_space(3))) void*)&Bs[buf][(i * 4 + w) * 512], 16, 0, 0);
    }
  };

  f32x4 acc[4][4] = {};
  stage(0, 0);
  for (int kt = 0; kt < 8; kt++) {
    int cur = kt & 1;
    if (kt < 7) {
      stage((kt + 1) << 6, cur ^ 1);
      asm volatile("s_waitcnt vmcnt(8)" ::: "memory");   // current tile done
    } else {
      asm volatile("s_waitcnt vmcnt(0)" ::: "memory");
    }
    __builtin_amdgcn_sched_barrier(0);
    __builtin_amdgcn_s_barrier();                        // raw: no auto-drain
    __builtin_amdgcn_sched_barrier(0);
    #pragma unroll
    for (int kk = 0; kk < 2; kk++) {                     // k halves (32 elems)
      bf16x8 aF[4], bF[4];
      #pragma unroll
      for (int m = 0; m < 4; m++) {
        int row = wr * 64 + m * 16 + cc;
        int cp = ((rb + kk * 4) ^ (cc & 7)) << 3;        // swizzled read
        aF[m] = *(bf16x8*)&As[cur][row * 64 + cp];
      }
      #pragma unroll
      for (int n = 0; n < 4; n++) {
        int row = wc * 64 + n * 16 + cc;
        int cp = ((rb + kk * 4) ^ (cc & 7)) << 3;
        bF[n] = *(bf16x8*)&Bs[cur][row * 64 + cp];
      }
      #pragma unroll
      for (int m = 0; m < 4; m++)
        #pragma unroll
        for (int n = 0; n < 4; n++)
          acc[m][n] = __builtin_amdgcn_mfma_f32_16x16x32_bf16(aF[m], bF[n], acc[m][n], 0, 0, 0);
    }
    __syncthreads();                                     // all reads done
  }

  if (MODE == 3) {
    int bb = n0 >> 11;
    int mat = e0 >> 9;
    int e0c = e0 & 511;
    if (mat == 2) {
      // V blocked: [B][H][L/64][DH][64]; l runs along j -> bf16x4 store
      #pragma unroll
      for (int n = 0; n < 4; n++) {
        int c = e0c + wc * 64 + n * 16 + cc;
        int h = c >> 6, dh = c & 63;
        float cp = 0.f;
        #pragma unroll
        for (int m = 0; m < 4; m++) {
          int l = (n0 + wr * 64 + m * 16 + rb * 4) & (Lc - 1);
          bf16x4 o4;
          o4[0] = (__bf16)acc[m][n][0]; o4[1] = (__bf16)acc[m][n][1];
          o4[2] = (__bf16)acc[m][n][2]; o4[3] = (__bf16)acc[m][n][3];
          size_t addr = ((((size_t)(bb * Hc + h)) * (Lc / 64) + (l >> 6)) * DHc + dh) * 64 + (l & 63);
          *(bf16x4*)&o_v[addr] = o4;
          cp += (acc[m][n][0] + acc[m][n][1]) + (acc[m][n][2] + acc[m][n][3]);
        }
        cp += __shfl_xor(cp, 16);
        cp += __shfl_xor(cp, 32);
        if (lane < 16) atomicAdd(&vm[(bb * Hc + h) * DHc + dh], cp);
      }
    } else {
      float sc = (mat == 0) ? QSCALE : 1.0f;
      u16* dst = (mat == 0) ? o_q : o_k;
      #pragma unroll
      for (int m = 0; m < 4; m++) {
        #pragma unroll
        for (int n = 0; n < 4; n++) {
          #pragma unroll
          for (int j = 0; j < 4; j++) {
            int r = n0 + wr * 64 + m * 16 + rb * 4 + j;
            int c = e0c + wc * 64 + n * 16 + cc;
            int ll = r & (Lc - 1);
            dst[(((size_t)(bb * Hc + (c >> 6))) * Lc + ll) * DHc + (c & 63)] = bf_bits(acc[m][n][j] * sc);
          }
        }
      }
    }
  } else {
    #pragma unroll
    for (int m = 0; m < 4; m++) {
      #pragma unroll
      for (int n = 0; n < 4; n++) {
        #pragma unroll
        for (int j = 0; j < 4; j++) {
          int r = n0 + wr * 64 + m * 16 + rb * 4 + j;
          int c = e0 + wc * 64 + n * 16 + cc;
          size_t o = (size_t)r * Dc + c;
          out_f[o] = acc[m][n][j] + res[o];
        }
      }
    }
  }
}

// ---------------------------------------------------------------------------
// Flash attention v11 (FROZEN champion, 71.3-72.4us): one wave per (bh,qt),
// QBLK=32, KVBLK=64, swapped QK^T in exp2 domain, blocked V, 2-deep K
// prefetch (named buffers), shuffle-free defer-max softmax, early V issue.
// ---------------------------------------------------------------------------
__global__ __launch_bounds__(64) void attn11(const u16* __restrict__ Q,
                                             const u16* __restrict__ K,
                                             const u16* __restrict__ VT,
                                             const float* __restrict__ vm,
                                             const u64* __restrict__ pmask,
                                             u16* __restrict__ out) {
  __shared__ u16 Ps[32 * PS];
  int lane = threadIdx.x;
  int cc = lane & 15, rb = lane >> 4;
  int bh = blockIdx.x;
  int qt = (int)gridDim.y - 1 - (int)blockIdx.y;     // heavy q-tiles first
  int q0 = qt * 32;
  int b = bh >> 3, h = bh & 7;
  const u16* Qb = Q + (size_t)bh * Lc * DHc;
  const u16* Kb = K + (size_t)bh * Lc * DHc;
  const u16* Vb = VT + (size_t)bh * Lc * DHc;        // blocked [L/64][DH][64]
  const u64* pmb = pmask + (b << 5);
  int nfull = q0 >> 6;                               // last tile index

  bf16x8 qF[2][2];
  #pragma unroll
  for (int qb = 0; qb < 2; qb++)
    #pragma unroll
    for (int kc = 0; kc < 2; kc++)
      qF[qb][kc] = *(const bf16x8*)&Qb[(size_t)(q0 + qb * 16 + cc) * DHc + kc * 32 + rb * 8];

  float mrow[2] = {MNEG, MNEG};
  float lrow[2] = {0.f, 0.f};
  f32x4 acc[2][4] = {};

  bf16x8 kfA[4][2], kfB[4][2];
  {
    const u16* kp = Kb;
    #pragma unroll
    for (int c = 0; c < 4; c++) {
      kfA[c][0] = *(const bf16x8*)&kp[(c * 16 + cc) * DHc + rb * 8];
      kfA[c][1] = *(const bf16x8*)&kp[(c * 16 + cc) * DHc + 32 + rb * 8];
    }
  }
  if (nfull >= 1) {
    const u16* kp = Kb + (size_t)64 * DHc;
    #pragma unroll
    for (int c = 0; c < 4; c++) {
      kfB[c][0] = *(const bf16x8*)&kp[(c * 16 + cc) * DHc + rb * 8];
      kfB[c][1] = *(const bf16x8*)&kp[(c * 16 + cc) * DHc + 32 + rb * 8];
    }
  }

  auto body = [&](int kt, bf16x8 (&kf)[4][2]) {
    int k0 = kt * 64;
    bool last = (kt == nfull);
    u64 pm = pmb[kt];
    const u16* vp = Vb + (size_t)kt * (DHc * 64);
    bf16x8 vf[2][4];
    #pragma unroll
    for (int kc = 0; kc < 2; kc++)
      #pragma unroll
      for (int d0 = 0; d0 < 4; d0++)
        vf[kc][d0] = *(const bf16x8*)&vp[(d0 * 16 + cc) * 64 + kc * 32 + rb * 8];

    f32x4 sq[2][4] = {};
    __builtin_amdgcn_s_setprio(1);
    #pragma unroll
    for (int c = 0; c < 4; c++) {
      #pragma unroll
      for (int qb = 0; qb < 2; qb++) {
        sq[qb][c] = __builtin_amdgcn_mfma_f32_16x16x32_bf16(kf[c][0], qF[qb][0], sq[qb][c], 0, 0, 0);
        sq[qb][c] = __builtin_amdgcn_mfma_f32_16x16x32_bf16(kf[c][1], qF[qb][1], sq[qb][c], 0, 0, 0);
      }
    }
    __builtin_amdgcn_s_setprio(0);
    if (kt + 2 <= nfull) {
      const u16* kp = Kb + (size_t)(k0 + 128) * DHc;
      #pragma unroll
      for (int c = 0; c < 4; c++) {
        kf[c][0] = *(const bf16x8*)&kp[(c * 16 + cc) * DHc + rb * 8];
        kf[c][1] = *(const bf16x8*)&kp[(c * 16 + cc) * DHc + 32 + rb * 8];
      }
    }
    if (pm) {
      #pragma unroll
      for (int c = 0; c < 4; c++) {
        u32 smr = (((u32)(pm >> (c * 16)) & 0xffffu) >> (rb * 4));
        #pragma unroll
        for (int qb = 0; qb < 2; qb++)
          #pragma unroll
          for (int j = 0; j < 4; j++)
            if ((smr >> j) & 1) sq[qb][c][j] = -INFINITY;
      }
    }
    if (last) {
      #pragma unroll
      for (int qb = 0; qb < 2; qb++) {
        int qrel = q0 + qb * 16 + cc - k0;
        #pragma unroll
        for (int c = 0; c < 4; c++)
          #pragma unroll
          for (int j = 0; j < 4; j++)
            if (c * 16 + rb * 4 + j > qrel) sq[qb][c][j] = -INFINITY;
      }
    }
    #pragma unroll
    for (int qb = 0; qb < 2; qb++) {
      float m0 = fmaxf(fmaxf(sq[qb][0][0], sq[qb][0][1]), fmaxf(sq[qb][0][2], sq[qb][0][3]));
      float m1 = fmaxf(fmaxf(sq[qb][1][0], sq[qb][1][1]), fmaxf(sq[qb][1][2], sq[qb][1][3]));
      float m2 = fmaxf(fmaxf(sq[qb][2][0], sq[qb][2][1]), fmaxf(sq[qb][2][2], sq[qb][2][3]));
      float m3 = fmaxf(fmaxf(sq[qb][3][0], sq[qb][3][1]), fmaxf(sq[qb][3][2], sq[qb][3][3]));
      float mx = fmaxf(fmaxf(m0, m1), fmaxf(m2, m3));
      mx = fmaxf(mx, __shfl_xor(mx, 16));
      mx = fmaxf(mx, __shfl_xor(mx, 32));
      if (!__all(mx <= mrow[qb] + 8.f)) {
        float nm = fmaxf(mrow[qb], mx);
        float alpha = exp2f(mrow[qb] - nm);
        lrow[qb] *= alpha;
        #pragma unroll
        for (int d0 = 0; d0 < 4; d0++)
          #pragma unroll
          for (int j = 0; j < 4; j++)
            acc[qb][d0][j] *= alpha;
        mrow[qb] = nm;
      }
      float rs = 0.f;
      #pragma unroll
      for (int c = 0; c < 4; c++) {
        f32x4 p;
        #pragma unroll
        for (int j = 0; j < 4; j++) p[j] = exp2f(sq[qb][c][j] - mrow[qb]);
        rs += (p[0] + p[1]) + (p[2] + p[3]);
        bf16x4 p4;
        p4[0] = (__bf16)p[0]; p4[1] = (__bf16)p[1];
        p4[2] = (__bf16)p[2]; p4[3] = (__bf16)p[3];
        *(bf16x4*)&Ps[(qb * 16 + cc) * PS + c * 16 + rb * 4] = p4;
      }
      rs += __shfl_xor(rs, 16);
      rs += __shfl_xor(rs, 32);
      lrow[qb] += rs;
    }
    asm volatile("s_waitcnt lgkmcnt(0)" ::: "memory");   // wave-local RAW on Ps
    __builtin_amdgcn_sched_barrier(0);                   // rule #18
    __builtin_amdgcn_s_setprio(1);
    #pragma unroll
    for (int kc = 0; kc < 2; kc++) {
      bf16x8 pF0 = *(bf16x8*)&Ps[(size_t)cc * PS + kc * 32 + rb * 8];
      bf16x8 pF1 = *(bf16x8*)&Ps[(size_t)(16 + cc) * PS + kc * 32 + rb * 8];
      #pragma unroll
      for (int d0 = 0; d0 < 4; d0++) {
        acc[0][d0] = __builtin_amdgcn_mfma_f32_16x16x32_bf16(vf[kc][d0], pF0, acc[0][d0], 0, 0, 0);
        acc[1][d0] = __builtin_amdgcn_mfma_f32_16x16x32_bf16(vf[kc][d0], pF1, acc[1][d0], 0, 0, 0);
      }
    }
    __builtin_amdgcn_s_setprio(0);
  };

  for (int kt = 0; kt <= nfull; kt += 2) {
    body(kt, kfA);
    if (kt + 1 <= nfull) body(kt + 1, kfB);
  }

  #pragma unroll
  for (int qb = 0; qb < 2; qb++) {
    int q = q0 + qb * 16 + cc;
    bool ok = lrow[qb] > 0.f;
    float inv = ok ? 1.0f / lrow[qb] : 0.f;
    #pragma unroll
    for (int d0 = 0; d0 < 4; d0++) {
      bf16x4 o4;
      #pragma unroll
      for (int j = 0; j < 4; j++) {
        float v = ok ? acc[qb][d0][j] * inv
                     : vm[bh * DHc + d0 * 16 + rb * 4 + j] * (1.0f / Lc);
        o4[j] = (__bf16)v;
      }
      *(bf16x4*)&out[((size_t)(b * Lc + q)) * Dc + h * DHc + d0 * 16 + rb * 4] = o4;
    }
  }
}

// ---------------------------------------------------------------------------
// Launch
// ---------------------------------------------------------------------------
extern "C" void kernel_launch(void* const* d_in, const int* in_sizes, int n_in,
                              void* d_out, int out_size, void* d_ws, size_t ws_size,
                              hipStream_t stream) {
  const float* x     = (const float*)d_in[0];
  const int*   tok   = (const int*)d_in[1];
  const float* Wq    = (const float*)d_in[2];
  const float* Wk    = (const float*)d_in[3];
  const float* Wv    = (const float*)d_in[4];
  const float* Wo    = (const float*)d_in[5];
  const float* gamma = (const float*)d_in[6];
  const float* beta  = (const float*)d_in[7];
  float* out = (float*)d_out;

  const size_t SEG = (size_t)NTOK * Dc;     // 4,194,304 elems
  const size_t WSEG = (size_t)Dc * Dc;      // 262,144 elems
  u16* xn   = (u16*)d_ws;
  u16* Qd   = xn + SEG;
  u16* Kd   = Qd + SEG;
  u16* VT   = Kd + SEG;                     // blocked [B][H][L/64][DH][64]
  u16* ao   = VT + SEG;
  u16* Wqkv = ao + SEG;                     // 3*WSEG (Q,K,V rows stacked)
  u16* Wob  = Wqkv + 3 * WSEG;
  float* vm = (float*)(Wob + WSEG);         // 2048 f32
  u64* pmarr = (u64*)(vm + (size_t)Bc * Hc * DHc);  // 128 u64

  prep2_kernel<<<3104, 256, 0, stream>>>(Wq, Wk, Wv, Wo,
                                         Wqkv, Wqkv + WSEG, Wqkv + 2 * WSEG, Wob,
                                         tok, pmarr, vm, x, gamma, beta, xn);

  dim3 gq(NTOK / 128, (3 * Dc) / 128);      // 64 x 12
  gemm_bf16<3><<<gq, 256, 0, stream>>>(xn, Wqkv, nullptr, nullptr, Qd, Kd, VT, vm);

  dim3 ga(Bc * Hc, Lc / 32);                // 32 x 64 one-wave blocks
  attn11<<<ga, 64, 0, stream>>>(Qd, Kd, VT, vm, pmarr, ao);

  dim3 gg(NTOK / 128, Dc / 128);            // 64 x 4
  gemm_bf16<0><<<gg, 256, 0, stream>>>(ao, Wob, x, out, nullptr, nullptr, nullptr, nullptr);
}